// Round 4
// baseline (3423.126 us; speedup 1.0000x reference)
//
#include <hip/hip_runtime.h>
#include <math.h>

typedef unsigned short u16;
typedef unsigned int u32;
typedef __bf16 bf16x8 __attribute__((ext_vector_type(8)));
typedef float floatx4 __attribute__((ext_vector_type(4)));

#define MFMA16(a, b, c) __builtin_amdgcn_mfma_f32_16x16x32_bf16((a), (b), (c), 0, 0, 0)

__device__ __forceinline__ float bf2f(u16 u) {
  u32 x = ((u32)u) << 16; float f; __builtin_memcpy(&f, &x, 4); return f;
}
__device__ __forceinline__ u16 f2bf(float f) {
  u32 x; __builtin_memcpy(&x, &f, 4);
  return (u16)((x + 0x7FFFu + ((x >> 16) & 1u)) >> 16);  // RNE
}
// diagnostic-only dual store (used by sentinels)
__device__ __forceinline__ void store_dual(u16* outp, float v) {
  u32 h = (u32)f2bf(v);
  *(u32*)outp = (h << 16) | h;
}
__device__ __forceinline__ bf16x8 ld8(const u16* p) { return *(const bf16x8*)p; }

__device__ __forceinline__ float wred64(float v) {
#pragma unroll
  for (int off = 32; off > 0; off >>= 1) v += __shfl_down(v, off, 64);
  return v;
}

// ---------------- diagnostics ----------------
__global__ void k_sentinel(u16* outp, float v) {
  if (threadIdx.x == 0 && blockIdx.x == 0) store_dual(outp, v);
}

// ---------------- input dtype detect: flag=1 if f32, 0 if bf16 ----------------
__global__ void k_detect(const u32* __restrict__ raw, int* __restrict__ flag) {
  if (threadIdx.x == 0 && blockIdx.x == 0) {
    int outliers = 0;
    for (int i = 0; i < 64; ++i) {
      u32 lo = raw[i] & 0xFFFFu;      // bf16-stream element 2i (low half if f32)
      int e = (int)((lo >> 7) & 0xFF);
      if (e < 100 || e > 150) ++outliers;   // N(0,1) bf16 exponents live in ~[119,130]
    }
    *flag = (outliers > 16) ? 1 : 0;
  }
}

// ---------------- dtype-aware convert-to-bf16 ----------------
__global__ void k_cvt(const float* __restrict__ inf_, const u16* __restrict__ inb,
                      u16* __restrict__ out, int n, const int* __restrict__ flag) {
  int i = blockIdx.x * 256 + threadIdx.x;
  if (i >= n) return;
  out[i] = (*flag) ? f2bf(inf_[i]) : inb[i];
}

// ---------------- transpose (bf16), out[c][r] = in[r][c] ----------------
__global__ void k_transpose(const u16* __restrict__ in, u16* __restrict__ out, int R, int C) {
  int i = blockIdx.x * 256 + threadIdx.x;
  if (i < R * C) { int r = i / C, c = i - r * C; out[c * R + r] = in[i]; }
}

// ---------------- start-vector MLP (1 block) -> ex0[128] ----------------
__global__ __launch_bounds__(256) void k_start(
    const u16* __restrict__ se,
    const u16* __restrict__ sw0, const u16* __restrict__ sb0,
    const u16* __restrict__ sw1, const u16* __restrict__ sb1,
    const u16* __restrict__ sw2, const u16* __restrict__ sb2,
    const u16* __restrict__ sw3, const u16* __restrict__ sb3,
    const u16* __restrict__ sw4, const u16* __restrict__ sb4,
    const u16* __restrict__ proj, float* __restrict__ ex0) {
  __shared__ float xa[256], xb[256], xc[256], red[256];
  const int tid = threadIdx.x;
  xa[tid] = bf2f(se[tid]);
  __syncthreads();
  float acc = bf2f(sb0[tid]);
  for (int k = 0; k < 256; ++k) acc += xa[k] * bf2f(sw0[k * 256 + tid]);
  xb[tid] = acc;  // f0 (Linear, no relu)
  __syncthreads();
  acc = bf2f(sb1[tid]);
  for (int k = 0; k < 256; ++k) acc += xb[k] * bf2f(sw1[k * 256 + tid]);
  xc[tid] = fmaxf(acc, 0.f);
  __syncthreads();
  acc = bf2f(sb2[tid]);
  for (int k = 0; k < 256; ++k) acc += xc[k] * bf2f(sw2[k * 256 + tid]);
  xa[tid] = fmaxf(acc, 0.f) + xb[tid];  // f1
  __syncthreads();
  acc = bf2f(sb3[tid]);
  for (int k = 0; k < 256; ++k) acc += xa[k] * bf2f(sw3[k * 256 + tid]);
  xc[tid] = fmaxf(acc, 0.f);
  __syncthreads();
  acc = bf2f(sb4[tid]);
  for (int k = 0; k < 256; ++k) acc += xc[k] * bf2f(sw4[k * 256 + tid]);
  xb[tid] = fmaxf(acc, 0.f) + xa[tid];  // f2
  __syncthreads();
  red[tid] = xb[tid] * xb[tid];
  __syncthreads();
  for (int s = 128; s > 0; s >>= 1) {
    if (tid < s) red[tid] += red[tid + s];
    __syncthreads();
  }
  const float rs = rsqrtf(red[0]);
  xa[tid] = xb[tid] * rs;
  __syncthreads();
  if (tid < 128) {
    float a = 0.f;
    for (int k = 0; k < 256; ++k) a += xa[k] * bf2f(proj[k * 128 + tid]);
    ex0[tid] = expf(a);
  }
}

// ---------------- preterminal MLP: ft = res(res(X0)) via MFMA ----------------
__global__ __launch_bounds__(256) void k_mlp(
    const u16* __restrict__ X0,
    const u16* __restrict__ w1T, const u16* __restrict__ b1,
    const u16* __restrict__ w2T, const u16* __restrict__ b2,
    const u16* __restrict__ w3T, const u16* __restrict__ b3,
    const u16* __restrict__ w4T, const u16* __restrict__ b4,
    u16* __restrict__ FT) {
  __shared__ __align__(16) u16 Y[2][64][264];
  const int tid = threadIdx.x, lane = tid & 63, w = tid >> 6;
  const int m16 = lane & 15, kg = lane >> 4;
  const int rbl = w * 16;
  const int rbg = blockIdx.x * 64 + rbl;
  const floatx4 z4 = {0.f, 0.f, 0.f, 0.f};
  floatx4 acc[16];

#pragma unroll
  for (int ct = 0; ct < 16; ++ct) acc[ct] = z4;
  for (int k0 = 0; k0 < 256; k0 += 32) {
    bf16x8 a = ld8(X0 + (size_t)(rbg + m16) * 256 + k0 + kg * 8);
#pragma unroll
    for (int ct = 0; ct < 16; ++ct)
      acc[ct] = MFMA16(a, ld8(w1T + (ct * 16 + m16) * 256 + k0 + kg * 8), acc[ct]);
  }
#pragma unroll
  for (int ct = 0; ct < 16; ++ct) {
    const int col = ct * 16 + m16;
    const float bv = bf2f(b1[col]);
#pragma unroll
    for (int r = 0; r < 4; ++r)
      Y[0][rbl + kg * 4 + r][col] = f2bf(fmaxf(acc[ct][r] + bv, 0.f));
  }
  __syncthreads();
#pragma unroll
  for (int ct = 0; ct < 16; ++ct) acc[ct] = z4;
  for (int k0 = 0; k0 < 256; k0 += 32) {
    bf16x8 a = *(const bf16x8*)(&Y[0][rbl + m16][k0 + kg * 8]);
#pragma unroll
    for (int ct = 0; ct < 16; ++ct)
      acc[ct] = MFMA16(a, ld8(w2T + (ct * 16 + m16) * 256 + k0 + kg * 8), acc[ct]);
  }
#pragma unroll
  for (int ct = 0; ct < 16; ++ct) {
    const int col = ct * 16 + m16;
    const float bv = bf2f(b2[col]);
#pragma unroll
    for (int r = 0; r < 4; ++r) {
      const int gr = rbg + kg * 4 + r;
      float v = fmaxf(acc[ct][r] + bv, 0.f) + bf2f(X0[(size_t)gr * 256 + col]);
      Y[1][rbl + kg * 4 + r][col] = f2bf(v);
    }
  }
  __syncthreads();
#pragma unroll
  for (int ct = 0; ct < 16; ++ct) acc[ct] = z4;
  for (int k0 = 0; k0 < 256; k0 += 32) {
    bf16x8 a = *(const bf16x8*)(&Y[1][rbl + m16][k0 + kg * 8]);
#pragma unroll
    for (int ct = 0; ct < 16; ++ct)
      acc[ct] = MFMA16(a, ld8(w3T + (ct * 16 + m16) * 256 + k0 + kg * 8), acc[ct]);
  }
#pragma unroll
  for (int ct = 0; ct < 16; ++ct) {
    const int col = ct * 16 + m16;
    const float bv = bf2f(b3[col]);
#pragma unroll
    for (int r = 0; r < 4; ++r)
      Y[0][rbl + kg * 4 + r][col] = f2bf(fmaxf(acc[ct][r] + bv, 0.f));
  }
  __syncthreads();
#pragma unroll
  for (int ct = 0; ct < 16; ++ct) acc[ct] = z4;
  for (int k0 = 0; k0 < 256; k0 += 32) {
    bf16x8 a = *(const bf16x8*)(&Y[0][rbl + m16][k0 + kg * 8]);
#pragma unroll
    for (int ct = 0; ct < 16; ++ct)
      acc[ct] = MFMA16(a, ld8(w4T + (ct * 16 + m16) * 256 + k0 + kg * 8), acc[ct]);
  }
#pragma unroll
  for (int ct = 0; ct < 16; ++ct) {
    const int col = ct * 16 + m16;
    const float bv = bf2f(b4[col]);
#pragma unroll
    for (int r = 0; r < 4; ++r) {
      const int rl = rbl + kg * 4 + r;
      float v = fmaxf(acc[ct][r] + bv, 0.f) + bf2f(Y[1][rl][col]);
      FT[(size_t)(rbg + kg * 4 + r) * 256 + col] = f2bf(v);
    }
  }
}

// ---------------- per-row 1/||x|| over 256 cols ----------------
__global__ __launch_bounds__(256) void k_rownorm(const u16* __restrict__ X,
                                                 float* __restrict__ rscale, int rows) {
  const int w = threadIdx.x >> 6, lane = threadIdx.x & 63;
  const int row = blockIdx.x * 4 + w;
  if (row >= rows) return;
  const u16* p = X + (size_t)row * 256 + lane * 4;
  float s = 0.f;
#pragma unroll
  for (int i = 0; i < 4; ++i) { float v = bf2f(p[i]); s += v * v; }
  s = wred64(s);
  if (lane == 0) rscale[row] = rsqrtf(s);
}

// ---------------- features: OUT[r][d] = exp(rscale[r] * X[r]·projT[d]) ----------------
__global__ __launch_bounds__(256) void k_feat(const u16* __restrict__ X,
                                              const float* __restrict__ rscale,
                                              const u16* __restrict__ PT,
                                              u16* __restrict__ OUT) {
  const int tid = threadIdx.x, lane = tid & 63, w = tid >> 6;
  const int m16 = lane & 15, kg = lane >> 4;
  const int rb = blockIdx.x * 64 + w * 16;
  const floatx4 z4 = {0.f, 0.f, 0.f, 0.f};
  floatx4 acc[8];
#pragma unroll
  for (int ct = 0; ct < 8; ++ct) acc[ct] = z4;
  for (int k0 = 0; k0 < 256; k0 += 32) {
    bf16x8 a = ld8(X + (size_t)(rb + m16) * 256 + k0 + kg * 8);
#pragma unroll
    for (int ct = 0; ct < 8; ++ct)
      acc[ct] = MFMA16(a, ld8(PT + (ct * 16 + m16) * 256 + k0 + kg * 8), acc[ct]);
  }
  float rs[4];
#pragma unroll
  for (int r = 0; r < 4; ++r) rs[r] = rscale[rb + kg * 4 + r];
#pragma unroll
  for (int ct = 0; ct < 8; ++ct)
#pragma unroll
    for (int r = 0; r < 4; ++r)
      OUT[(size_t)(rb + kg * 4 + r) * 128 + ct * 16 + m16] = f2bf(expf(acc[ct][r] * rs[r]));
}

// ---------------- term features fused with column-sum ----------------
__global__ __launch_bounds__(256) void k_feat_colsum(const u16* __restrict__ X,
                                                     const float* __restrict__ rscale,
                                                     const u16* __restrict__ PT,
                                                     float* __restrict__ part) {
  __shared__ float cred[128];
  const int tid = threadIdx.x, lane = tid & 63, w = tid >> 6;
  const int m16 = lane & 15, kg = lane >> 4;
  const int rb = blockIdx.x * 64 + w * 16;
  if (tid < 128) cred[tid] = 0.f;
  __syncthreads();
  const floatx4 z4 = {0.f, 0.f, 0.f, 0.f};
  floatx4 acc[8];
#pragma unroll
  for (int ct = 0; ct < 8; ++ct) acc[ct] = z4;
  for (int k0 = 0; k0 < 256; k0 += 32) {
    bf16x8 a = ld8(X + (size_t)(rb + m16) * 256 + k0 + kg * 8);
#pragma unroll
    for (int ct = 0; ct < 8; ++ct)
      acc[ct] = MFMA16(a, ld8(PT + (ct * 16 + m16) * 256 + k0 + kg * 8), acc[ct]);
  }
  float rs[4];
#pragma unroll
  for (int r = 0; r < 4; ++r) rs[r] = rscale[rb + kg * 4 + r];
#pragma unroll
  for (int ct = 0; ct < 8; ++ct) {
    float s = 0.f;
#pragma unroll
    for (int r = 0; r < 4; ++r) s += expf(acc[ct][r] * rs[r]);
    atomicAdd(&cred[ct * 16 + m16], s);
  }
  __syncthreads();
  if (tid < 128) part[(size_t)blockIdx.x * 128 + tid] = cred[tid];
}

__global__ void k_colred(const float* __restrict__ part, float* __restrict__ out, int nblk) {
  const int tid = threadIdx.x;
  if (tid < 128) {
    float s = 0.f;
    for (int b = 0; b < nblk; ++b) s += part[(size_t)b * 128 + tid];
    out[tid] = s;
  }
}

// ---------------- gathered token features ----------------
__global__ __launch_bounds__(256) void k_feat_gather(const int* __restrict__ text,
                                                     const u16* __restrict__ TE,
                                                     const float* __restrict__ rs_term,
                                                     const u16* __restrict__ PT,
                                                     u16* __restrict__ Btok) {
  const int tid = threadIdx.x, lane = tid & 63, w = tid >> 6;
  const int m16 = lane & 15, kg = lane >> 4;
  const int rb = blockIdx.x * 64 + w * 16;
  const int ia = rb + m16;
  const int tok_a = text[(ia & 15) * 256 + (ia >> 4)];
  const floatx4 z4 = {0.f, 0.f, 0.f, 0.f};
  floatx4 acc[8];
#pragma unroll
  for (int ct = 0; ct < 8; ++ct) acc[ct] = z4;
  for (int k0 = 0; k0 < 256; k0 += 32) {
    bf16x8 a = ld8(TE + (size_t)tok_a * 256 + k0 + kg * 8);
#pragma unroll
    for (int ct = 0; ct < 8; ++ct)
      acc[ct] = MFMA16(a, ld8(PT + (ct * 16 + m16) * 256 + k0 + kg * 8), acc[ct]);
  }
  float rs[4];
#pragma unroll
  for (int r = 0; r < 4; ++r) {
    const int io = rb + kg * 4 + r;
    rs[r] = rs_term[text[(io & 15) * 256 + (io >> 4)]];
  }
#pragma unroll
  for (int ct = 0; ct < 8; ++ct)
#pragma unroll
    for (int r = 0; r < 4; ++r)
      Btok[(size_t)(rb + kg * 4 + r) * 128 + ct * 16 + m16] = f2bf(expf(acc[ct][r] * rs[r]));
}

// ---------------- colsum (ByN -> SBN) ----------------
__global__ __launch_bounds__(256) void k_colsum(const u16* __restrict__ X,
                                                float* __restrict__ out, int rows) {
  __shared__ float red[256];
  const int tid = threadIdx.x, d = tid & 127, g = tid >> 7;
  const int r0 = blockIdx.x * 256 + g, r1 = blockIdx.x * 256 + 256;
  float s = 0.f;
  for (int r = r0; r < r1; r += 2) s += bf2f(X[(size_t)r * 128 + d]);
  red[tid] = s;
  __syncthreads();
  if (tid < 128) atomicAdd(out + tid, red[tid] + red[tid + 128]);
}

// ---------------- per-state scalars ----------------
__global__ __launch_bounds__(256) void k_vecdots(
    const u16* __restrict__ AxS, const u16* __restrict__ AxP, const u16* __restrict__ ByN,
    const float* __restrict__ SBN, const float* __restrict__ SBT, const float* __restrict__ ex0,
    float* __restrict__ recip_r, float* __restrict__ recip_den,
    float* __restrict__ start_raw) {
  const int w = threadIdx.x >> 6, lane = threadIdx.x & 63;
  const int c = blockIdx.x * 4 + w;
  const int d = lane * 2;
  float a0 = bf2f(AxS[(size_t)c * 128 + d]), a1 = bf2f(AxS[(size_t)c * 128 + d + 1]);
  float t = wred64(a0 * SBN[d] + a1 * SBN[d + 1]);
  float p0 = bf2f(AxP[(size_t)c * 128 + d]), p1 = bf2f(AxP[(size_t)c * 128 + d + 1]);
  float p = wred64(p0 * SBT[d] + p1 * SBT[d + 1]);
  float y0 = bf2f(ByN[(size_t)c * 128 + d]), y1 = bf2f(ByN[(size_t)c * 128 + d + 1]);
  float s = wred64(y0 * ex0[d] + y1 * ex0[d + 1]);
  if (lane == 0) {
    recip_r[c] = 1.0f / t;
    recip_den[c] = 1.0f / p;
    start_raw[c] = s;
  }
}

__global__ void k_ssum(const float* __restrict__ start_raw, float* __restrict__ ssum) {
  __shared__ float red[256];
  const int tid = threadIdx.x;
  float s = 0.f;
  for (int i = tid; i < 4096; i += 256) s += start_raw[i];
  red[tid] = s;
  __syncthreads();
  for (int st = 128; st > 0; st >>= 1) {
    if (tid < st) red[tid] += red[tid + st];
    __syncthreads();
  }
  if (tid == 0) ssum[0] = red[0];
}

// ---------- wave-0 emission tile for timestep t ----------
__device__ __forceinline__ void emis16(const u16* __restrict__ Btok,
                                       const u16 (*AxPs)[128],
                                       const float* __restrict__ recip_den,
                                       int cbase, int t, int m16, int kg,
                                       float* emsh) {
  floatx4 acc = {0.f, 0.f, 0.f, 0.f};
#pragma unroll
  for (int k0 = 0; k0 < 128; k0 += 32)
    acc = MFMA16(ld8(Btok + (size_t)(t * 16 + m16) * 128 + k0 + kg * 8),
                 *(const bf16x8*)(&AxPs[m16][k0 + kg * 8]), acc);
  const float rd = recip_den[cbase + m16];
#pragma unroll
  for (int r = 0; r < 4; ++r) emsh[(kg * 4 + r) * 16 + m16] = acc[r] * rd;
}

// ---------------- TT[c'][c] = trans[c][c'] (materialized) ----------------
__global__ __launch_bounds__(256) void k_pair(const u16* __restrict__ A, const u16* __restrict__ B,
                                              const float* __restrict__ cscale,
                                              u16* __restrict__ OUT) {
  const int tid = threadIdx.x, lane = tid & 63, w = tid >> 6;
  const int m16 = lane & 15, kg = lane >> 4;
  const int mb = blockIdx.y * 128 + w * 32;
  const int nb = blockIdx.x * 128;
  const floatx4 z4 = {0.f, 0.f, 0.f, 0.f};
  floatx4 acc[2][8];
#pragma unroll
  for (int rt = 0; rt < 2; ++rt)
#pragma unroll
    for (int ct = 0; ct < 8; ++ct) acc[rt][ct] = z4;
  for (int k0 = 0; k0 < 128; k0 += 32) {
    bf16x8 a0 = ld8(A + (size_t)(mb + m16) * 128 + k0 + kg * 8);
    bf16x8 a1 = ld8(A + (size_t)(mb + 16 + m16) * 128 + k0 + kg * 8);
#pragma unroll
    for (int ct = 0; ct < 8; ++ct) {
      bf16x8 bb = ld8(B + (size_t)(nb + ct * 16 + m16) * 128 + k0 + kg * 8);
      acc[0][ct] = MFMA16(a0, bb, acc[0][ct]);
      acc[1][ct] = MFMA16(a1, bb, acc[1][ct]);
    }
  }
  float cs[8];
#pragma unroll
  for (int ct = 0; ct < 8; ++ct) cs[ct] = cscale[nb + ct * 16 + m16];
#pragma unroll
  for (int rt = 0; rt < 2; ++rt)
#pragma unroll
    for (int ct = 0; ct < 8; ++ct)
#pragma unroll
      for (int r = 0; r < 4; ++r)
        OUT[(size_t)(mb + rt * 16 + kg * 4 + r) * 4096 + nb + ct * 16 + m16] =
            f2bf(acc[rt][ct][r] * cs[ct]);
}

// ---------------- one HMM step per launch ----------------
__global__ __launch_bounds__(256) void k_step(
    const u16* __restrict__ TT, const u16* __restrict__ Btok, const u16* __restrict__ AxP,
    const float* __restrict__ recip_den, const float* __restrict__ start_raw,
    const u16* __restrict__ Uprev, u16* __restrict__ Ucur,
    float* __restrict__ Spart, float* __restrict__ Ev, int t) {
  __shared__ __align__(16) u16 AxPs[16][128];
  __shared__ __align__(16) float red[4][256];
  __shared__ float red2[256];
  __shared__ float emsh[256];
  __shared__ float recipS[16];
  const int tid = threadIdx.x, lane = tid & 63, w = tid >> 6;
  const int m16 = lane & 15, kg = lane >> 4;
  const int b = blockIdx.x, cbase = b * 16;
  const floatx4 z4 = {0.f, 0.f, 0.f, 0.f};

  {
    const int r = tid >> 4, d = (tid & 15) * 8;
    *(uint4*)(&AxPs[r][d]) = *(const uint4*)(AxP + (size_t)(cbase + r) * 128 + d);
  }
  __syncthreads();
  if (w == 0) emis16(Btok, AxPs, recip_den, cbase, t, m16, kg, emsh);
  if (t == 0) {
    __syncthreads();
    const int n = tid >> 4, c = tid & 15;
    float u = start_raw[cbase + c] * emsh[tid];
    Ucur[n * 4096 + cbase + c] = f2bf(u);
    red2[tid] = u;
    __syncthreads();
    if (tid < 16) {
      float s = 0.f;
      for (int j = 0; j < 16; ++j) s += red2[tid * 16 + j];
      Spart[b * 16 + tid] = s;
    }
    return;
  }
  {
    const int n = tid & 15, g = tid >> 4;
    const float* sp = Spart + ((t - 1) & 1) * 4096;
    float ps = 0.f;
#pragma unroll
    for (int j = 0; j < 16; ++j) ps += sp[(g * 16 + j) * 16 + n];
    red2[tid] = ps;
  }
  __syncthreads();
  if (tid < 16) {
    float s = 0.f;
#pragma unroll
    for (int g = 0; g < 16; ++g) s += red2[g * 16 + tid];
    recipS[tid] = 1.0f / s;
    if (b == 0) Ev[tid] += logf(s);
  }
  {
    const int kw = w * 1024 + kg * 8;
    floatx4 acc0 = z4, acc1 = z4;
    const u16* arow = Uprev + m16 * 4096 + kw;
    const u16* brow = TT + (size_t)(cbase + m16) * 4096 + kw;  // B[n=m16][k]
#pragma unroll 4
    for (int kk = 0; kk < 1024; kk += 64) {
      acc0 = MFMA16(ld8(arow + kk), ld8(brow + kk), acc0);
      acc1 = MFMA16(ld8(arow + kk + 32), ld8(brow + kk + 32), acc1);
    }
    acc0 = acc0 + acc1;
#pragma unroll
    for (int r = 0; r < 4; ++r) red[w][(kg * 4 + r) * 16 + m16] = acc0[r];
  }
  __syncthreads();
  {
    const int n = tid >> 4, c = tid & 15;
    float v = red[0][tid] + red[1][tid] + red[2][tid] + red[3][tid];
    float u = v * recipS[n] * emsh[tid];
    Ucur[n * 4096 + cbase + c] = f2bf(u);
    red2[tid] = u;
  }
  __syncthreads();
  if (tid < 16) {
    float s = 0.f;
    for (int j = 0; j < 16; ++j) s += red2[tid * 16 + j];
    Spart[(t & 1) * 4096 + b * 16 + tid] = s;
  }
}

__global__ __launch_bounds__(256) void k_fin(const float* __restrict__ Spart,
                                             const float* __restrict__ Ev,
                                             const float* __restrict__ ssum,
                                             const int* __restrict__ flag,
                                             u16* __restrict__ outp) {
  __shared__ float red2[256];
  __shared__ float fin[16];
  const int tid = threadIdx.x;
  const int n = tid & 15, g = tid >> 4;
  const float* sp = Spart + 4096;  // t=255
  float ps = 0.f;
  for (int j = 0; j < 16; ++j) ps += sp[(g * 16 + j) * 16 + n];
  red2[tid] = ps;
  __syncthreads();
  if (tid < 16) {
    float s = 0.f;
    for (int g2 = 0; g2 < 16; ++g2) s += red2[g2 * 16 + tid];
    fin[tid] = Ev[tid] + logf(s);
  }
  __syncthreads();
  if (tid == 0) {
    float ev = 0.f;
    for (int i = 0; i < 16; ++i) ev += fin[i];
    ev -= 16.0f * logf(ssum[0]);
    if (!(ev == ev) || fabsf(ev) > 1e37f)      // NaN/inf diagnostic
      ev = -12345.0f - 1000.0f * (float)(*flag);
    if (*flag) *(float*)outp = ev;             // f32 output
    else       outp[0] = f2bf(ev);             // bf16 output
  }
}

extern "C" void kernel_launch(void* const* d_in, const int* in_sizes, int n_in,
                              void* d_out, int out_size, void* d_ws, size_t ws_size,
                              hipStream_t stream) {
  (void)out_size;
  u16* outp = (u16*)d_out;
  if (n_in != 26 || in_sizes[25] != 128 * 256) {
    k_sentinel<<<1, 1, 0, stream>>>(outp, 5000.0f + (float)n_in);
    return;
  }
  const int* text = (const int*)d_in[0];

  char* base = (char*)d_ws;
  size_t off = 0;
  auto take = [&](size_t bytes) -> char* {
    char* p = base + off;
    off = (off + bytes + 255) & ~(size_t)255;
    return p;
  };
  int* flag = (int*)take(256);
  // converted bf16 copies of all float inputs
  u16* c_se   = (u16*)take(256 * 2);
  u16* c_w[18];  // sw0,sb0,...,sw4,sb4, tw1,tb1,...,tw4,tb4 (d_in[3..20])
  for (int i = 0; i < 18; ++i) c_w[i] = (u16*)take(((i & 1) ? 256 : 65536) * 2);
  u16* c_state = (u16*)take((size_t)1048576 * 2);
  u16* c_next  = (u16*)take((size_t)1048576 * 2);
  u16* c_pre   = (u16*)take((size_t)1048576 * 2);
  u16* c_term  = (u16*)take((size_t)8192000 * 2);
  u16* c_proj  = (u16*)take((size_t)32768 * 2);
  // pipeline buffers
  u16* projT  = (u16*)take(128 * 256 * 2);
  u16* twT1   = (u16*)take(65536 * 2);
  u16* twT2   = (u16*)take(65536 * 2);
  u16* twT3   = (u16*)take(65536 * 2);
  u16* twT4   = (u16*)take(65536 * 2);
  u16* ft     = (u16*)take((size_t)4096 * 256 * 2);
  float* rs_state = (float*)take(4096 * 4);
  float* rs_next  = (float*)take(4096 * 4);
  float* rs_ft    = (float*)take(4096 * 4);
  float* rs_term  = (float*)take(32000 * 4);
  u16* AxS    = (u16*)take((size_t)4096 * 128 * 2);
  u16* ByN    = (u16*)take((size_t)4096 * 128 * 2);
  u16* AxP    = (u16*)take((size_t)4096 * 128 * 2);
  u16* Btok   = (u16*)take((size_t)4096 * 128 * 2);
  float* SBTpart = (float*)take(500 * 128 * 4);
  float* zreg = (float*)take(2048);  // SBN[128] | SBT[128] | ssum[1] | Ev[16]
  float* SBN = zreg, *SBT = zreg + 128, *ssum = zreg + 256, *Ev = zreg + 257;
  float* recip_r   = (float*)take(4096 * 4);
  float* recip_den = (float*)take(4096 * 4);
  float* start_raw = (float*)take(4096 * 4);
  float* ex0       = (float*)take(128 * 4);
  u16* U0     = (u16*)take(16 * 4096 * 2);
  u16* U1     = (u16*)take(16 * 4096 * 2);
  float* Spart = (float*)take(2 * 4096 * 4);
  u16* TT     = (u16*)take((size_t)4096 * 4096 * 2);

  const float ws_mb = (float)(ws_size >> 20) > 900.f ? 900.f : (float)(ws_size >> 20);
  if (off > ws_size) {
    k_sentinel<<<1, 1, 0, stream>>>(outp, 1000.0f + ws_mb);
    return;
  }

  k_detect<<<1, 64, 0, stream>>>((const u32*)d_in[25], flag);
  k_sentinel<<<1, 1, 0, stream>>>(outp, -7777.0f);  // breadcrumb
  hipMemsetAsync(zreg, 0, 2048, stream);

  auto cvt = [&](const void* p, u16* dst, int n) {
    k_cvt<<<(n + 255) / 256, 256, 0, stream>>>((const float*)p, (const u16*)p, dst, n, flag);
  };
  cvt(d_in[2], c_se, 256);
  for (int i = 0; i < 18; ++i) cvt(d_in[3 + i], c_w[i], (i & 1) ? 256 : 65536);
  cvt(d_in[21], c_state, 1048576);
  cvt(d_in[22], c_next, 1048576);
  cvt(d_in[23], c_pre, 1048576);
  cvt(d_in[24], c_term, 8192000);
  cvt(d_in[25], c_proj, 32768);

  u16 *c_sw0 = c_w[0], *c_sb0 = c_w[1], *c_sw1 = c_w[2], *c_sb1 = c_w[3];
  u16 *c_sw2 = c_w[4], *c_sb2 = c_w[5], *c_sw3 = c_w[6], *c_sb3 = c_w[7];
  u16 *c_sw4 = c_w[8], *c_sb4 = c_w[9];
  u16 *c_tw1 = c_w[10], *c_tb1 = c_w[11], *c_tw2 = c_w[12], *c_tb2 = c_w[13];
  u16 *c_tw3 = c_w[14], *c_tb3 = c_w[15], *c_tw4 = c_w[16], *c_tb4 = c_w[17];

  k_transpose<<<128, 256, 0, stream>>>(c_proj, projT, 256, 128);
  k_transpose<<<256, 256, 0, stream>>>(c_tw1, twT1, 256, 256);
  k_transpose<<<256, 256, 0, stream>>>(c_tw2, twT2, 256, 256);
  k_transpose<<<256, 256, 0, stream>>>(c_tw3, twT3, 256, 256);
  k_transpose<<<256, 256, 0, stream>>>(c_tw4, twT4, 256, 256);
  k_start<<<1, 256, 0, stream>>>(c_se, c_sw0, c_sb0, c_sw1, c_sb1, c_sw2, c_sb2,
                                 c_sw3, c_sb3, c_sw4, c_sb4, c_proj, ex0);
  k_mlp<<<64, 256, 0, stream>>>(c_pre, twT1, c_tb1, twT2, c_tb2, twT3, c_tb3, twT4, c_tb4, ft);
  k_rownorm<<<1024, 256, 0, stream>>>(c_state, rs_state, 4096);
  k_rownorm<<<1024, 256, 0, stream>>>(c_next, rs_next, 4096);
  k_rownorm<<<1024, 256, 0, stream>>>(ft, rs_ft, 4096);
  k_rownorm<<<8000, 256, 0, stream>>>(c_term, rs_term, 32000);
  k_feat<<<64, 256, 0, stream>>>(c_state, rs_state, projT, AxS);
  k_feat<<<64, 256, 0, stream>>>(c_next, rs_next, projT, ByN);
  k_feat<<<64, 256, 0, stream>>>(ft, rs_ft, projT, AxP);
  k_feat_colsum<<<500, 256, 0, stream>>>(c_term, rs_term, projT, SBTpart);
  k_colred<<<1, 256, 0, stream>>>(SBTpart, SBT, 500);
  k_feat_gather<<<64, 256, 0, stream>>>(text, c_term, rs_term, projT, Btok);
  k_colsum<<<16, 256, 0, stream>>>(ByN, SBN, 4096);
  k_vecdots<<<1024, 256, 0, stream>>>(AxS, AxP, ByN, SBN, SBT, ex0, recip_r, recip_den,
                                      start_raw);
  k_ssum<<<1, 256, 0, stream>>>(start_raw, ssum);

  k_pair<<<dim3(32, 32), 256, 0, stream>>>(ByN, AxS, recip_r, TT);  // TT[c'][c] = trans^T
  k_step<<<256, 256, 0, stream>>>(TT, Btok, AxP, recip_den, start_raw, U0, U0, Spart, Ev, 0);
  for (int t = 1; t < 256; ++t) {
    const u16* up = ((t - 1) & 1) ? U1 : U0;
    u16* uc = (t & 1) ? U1 : U0;
    k_step<<<256, 256, 0, stream>>>(TT, Btok, AxP, recip_den, start_raw, up, uc, Spart, Ev, t);
  }
  k_fin<<<1, 256, 0, stream>>>(Spart, Ev, ssum, flag, outp);
}